// Round 7
// baseline (113.708 us; speedup 1.0000x reference)
//
#include <hip/hip_runtime.h>

// ---------------- constants / ws layout (floats) ----------------
#define TT_ISTRIDE 672             // Tt per-i stride = 8 r * 84 padded j
#define TT_ELEMS (4 * 81 * 672)    // 217728
#define WS_HT 217728               // h_t: [4 a][36 q][8192 b] = 1179648 floats
#define WS_RIS (217728 + 1179648)  // risP: [4 iq][4 a][8192 b][8 r]
#define RIS_Q 262144               // one iq partial = 4*8192*8

// Transpose T[a][q0][q1][q2][q3][r] -> Tt[a][i][r][84]; j in three 28-wide
// 16B-aligned thirds: col = jt*28 + (j - jt*27); slot 27 of each third = 0.
__global__ void t_transpose(const float* __restrict__ T, float* __restrict__ Tt) {
    int idx = blockIdx.x * 256 + threadIdx.x;
    if (idx >= TT_ELEMS) return;
    int col  = idx % 84;
    int t1   = idx / 84;
    int r    = t1 & 7;
    int rest = t1 / 8;  // a*81 + i
    int jt   = col / 28;
    int kk   = col - jt * 28;
    Tt[idx] = (kk < 27) ? T[rest * 648 + (jt * 27 + kk) * 8 + r] : 0.0f;
}

#define GLL(gsrc, ldst) __builtin_amdgcn_global_load_lds( \
    (const __attribute__((address_space(1))) void*)(gsrc), \
    (__attribute__((address_space(3))) void*)(ldst), 16, 0, 0)

#define KEEP(x) asm volatile("" : "+v"(x))

// ---------------- K1: phase X ----------------
// Block: 128 b x 1 c x all 4 a; 512 thr: thread (b=t&127, a=t>>7), acc[8 r].
// nh k-windows (64 h) via GLL, XOR-swizzled SOURCE + linear dest (rule 21),
// read back per-lane b128 (1 DS per 32 FMA). U via wave-uniform VECTOR float4
// loads (vmcnt broadcast, L1-hot) -> no SMEM/lgkm mixing, no LDS round-trip.
__global__ __launch_bounds__(512, 2) void k1_phasex(
    const float* __restrict__ nh, const float* __restrict__ U,
    const float* __restrict__ bi, float* __restrict__ h_t) {
    __shared__ float nh_s[2][8192];   // 2 x 32 KB: [128 b][64 h] (swizzled cols)
    const int t   = threadIdx.x;
    const int bid = blockIdx.x;
    const int bg  = (bid & 7) * 8 + ((bid >> 3) & 7);  // same-bg blocks share XCD
    const int c   = bid >> 6;
    const int b0  = bg << 7;
    const int b   = t & 127;
    const int a   = t >> 7;

    float acc[8];
    {
        const float* bp = bi + (((c << 2) + a) << 3);
        #pragma unroll
        for (int r = 0; r < 8; ++r) acc[r] = bp[r];
    }

    // stage window 0 (4 GLL/thread; src col pre-swizzled: dest slot sl holds
    // logical k-quad sl^(bl&15) -> read at (k4^(b&15)) hits 4-way max conflict)
    {
        #pragma unroll
        for (int rep = 0; rep < 4; ++rep) {
            int tt = t + (rep << 9);
            int bl = tt >> 4, sl = tt & 15;
            const float* s = nh + (size_t)(b0 + bl) * 1024 + (c << 8)
                           + ((sl ^ (bl & 15)) << 2);
            GLL(s, &nh_s[0][tt << 2]);
        }
    }

    #pragma unroll 1
    for (int w = 0; w < 4; ++w) {
        if (w < 3) {
            #pragma unroll
            for (int rep = 0; rep < 4; ++rep) {
                int tt = t + (rep << 9);
                int bl = tt >> 4, sl = tt & 15;
                const float* s = nh + (size_t)(b0 + bl) * 1024 + (c << 8)
                               + ((w + 1) << 6) + ((sl ^ (bl & 15)) << 2);
                GLL(s, &nh_s[(w + 1) & 1][tt << 2]);
            }
            asm volatile("s_waitcnt vmcnt(4)" ::: "memory");  // window w landed
        } else {
            asm volatile("s_waitcnt vmcnt(0)" ::: "memory");
        }
        __builtin_amdgcn_s_barrier();
        asm volatile("" ::: "memory");

        const float* Up = U + (((c << 2) + a) << 11) + (w << 9);  // [64h][8r]
        const float* ap = &nh_s[w & 1][b << 6];
        #pragma unroll 4
        for (int k4 = 0; k4 < 16; ++k4) {
            float4 A = *(const float4*)(ap + ((k4 ^ (b & 15)) << 2));
            const float4* up = (const float4*)(Up + (k4 << 5));
            float4 u0 = up[0], u1 = up[1], u2 = up[2], u3 = up[3];
            float4 u4 = up[4], u5 = up[5], u6 = up[6], u7 = up[7];
            acc[0]=fmaf(A.x,u0.x,acc[0]); acc[1]=fmaf(A.x,u0.y,acc[1]);
            acc[2]=fmaf(A.x,u0.z,acc[2]); acc[3]=fmaf(A.x,u0.w,acc[3]);
            acc[4]=fmaf(A.x,u1.x,acc[4]); acc[5]=fmaf(A.x,u1.y,acc[5]);
            acc[6]=fmaf(A.x,u1.z,acc[6]); acc[7]=fmaf(A.x,u1.w,acc[7]);
            acc[0]=fmaf(A.y,u2.x,acc[0]); acc[1]=fmaf(A.y,u2.y,acc[1]);
            acc[2]=fmaf(A.y,u2.z,acc[2]); acc[3]=fmaf(A.y,u2.w,acc[3]);
            acc[4]=fmaf(A.y,u3.x,acc[4]); acc[5]=fmaf(A.y,u3.y,acc[5]);
            acc[6]=fmaf(A.y,u3.z,acc[6]); acc[7]=fmaf(A.y,u3.w,acc[7]);
            acc[0]=fmaf(A.z,u4.x,acc[0]); acc[1]=fmaf(A.z,u4.y,acc[1]);
            acc[2]=fmaf(A.z,u4.z,acc[2]); acc[3]=fmaf(A.z,u4.w,acc[3]);
            acc[4]=fmaf(A.z,u5.x,acc[4]); acc[5]=fmaf(A.z,u5.y,acc[5]);
            acc[6]=fmaf(A.z,u5.z,acc[6]); acc[7]=fmaf(A.z,u5.w,acc[7]);
            acc[0]=fmaf(A.w,u6.x,acc[0]); acc[1]=fmaf(A.w,u6.y,acc[1]);
            acc[2]=fmaf(A.w,u6.z,acc[2]); acc[3]=fmaf(A.w,u6.w,acc[3]);
            acc[4]=fmaf(A.w,u7.x,acc[4]); acc[5]=fmaf(A.w,u7.y,acc[5]);
            acc[6]=fmaf(A.w,u7.z,acc[6]); acc[7]=fmaf(A.w,u7.w,acc[7]);
        }
        asm volatile("" ::: "memory");
        __builtin_amdgcn_s_barrier();
    }

    // h_t[a][c*9 + r][b0+b] = acc[r] ; ones row at c*9+8  (coalesced per (a,r))
    size_t hb = ((size_t)a * 36 + (size_t)c * 9) * 8192 + b0 + b;
    #pragma unroll
    for (int r = 0; r < 8; ++r) h_t[hb + (size_t)r * 8192] = acc[r];
    h_t[hb + (size_t)8 * 8192] = 1.0f;
}

// ---------------- K2: chain contraction ----------------
// Block: 256 b x 1 a x 1 i-quarter; 512 thr = 8 waves; wave w owns r=w; lane
// owns 4 batches. T chunks (5-6 i) dbuf'd via GLL+vmcnt(2). h0/h1 from small
// LDS h_s (lane-stride-1); h2/h3 pinned VGPRs loaded from GLOBAL (can't be
// rematerialized back to LDS - r5 lesson). grid 512 -> 2 blk/CU, 4 waves/SIMD.
__global__ __launch_bounds__(512, 4) void k2_chain(
    const float* __restrict__ Tt, const float* __restrict__ h_t,
    float* __restrict__ risP) {
    __shared__ float tc[2][4096];     // 32 KB (chunk max 6i = 4032 + pad)
    __shared__ float h_s[18 * 256];   // 18 KB: rows 0..8 = h0, 9..17 = h1
    const int t    = threadIdx.x;
    const int lane = t & 63;
    const int widr = t >> 6;
    const int bid  = blockIdx.x;
    const int bg   = (bid & 7) * 4 + ((bid >> 3) & 3);  // same-bg -> same XCD
    const int rest = bid >> 5;
    const int a    = rest >> 2;
    const int iq   = rest & 3;
    const int b0   = bg << 8;
    const int i_base = iq * 20;       // i in [iq*20, iq*20+20) (+1 for iq=3)

    const float* Tw = Tt + (size_t)a * 54432;

    // prologue: stage chunk 0 (2 GLL/thread, uniform -> vmcnt count exact)
    {
        const float* s = Tw + (size_t)i_base * 672;
        GLL(s + 4 * t, tc[0] + 4 * t);
        GLL(s + 4 * (512 + t), tc[0] + 4 * (512 + t));
    }
    // stage h_s (18 rows x 256 b, coalesced f4)
    for (int idx = t; idx < 1152; idx += 512) {
        int row = idx >> 6, c4 = (idx & 63) << 2;
        float4 v = *(const float4*)(h_t + ((size_t)a * 36 + row) * 8192 + b0 + c4);
        *(float4*)(&h_s[row * 256 + c4]) = v;
    }
    // pin h2,h3 from global (72 VGPR)
    float h2v[4][9], h3v[4][9];
    #pragma unroll
    for (int k = 0; k < 4; ++k) {
        #pragma unroll
        for (int q = 0; q < 9; ++q) {
            h2v[k][q] = h_t[((size_t)a * 36 + 18 + q) * 8192 + b0 + lane + 64 * k];
            h3v[k][q] = h_t[((size_t)a * 36 + 27 + q) * 8192 + b0 + lane + 64 * k];
        }
    }
    #pragma unroll
    for (int k = 0; k < 4; ++k) {
        #pragma unroll
        for (int q = 0; q < 9; ++q) { KEEP(h2v[k][q]); KEEP(h3v[k][q]); }
    }

    float A[4] = {0.f, 0.f, 0.f, 0.f};
    __syncthreads();   // h_s ready; drains prologue GLL + pin loads

    int q0 = i_base / 9, q1 = i_base - 9 * (i_base / 9);

    #pragma unroll 1
    for (int ch = 0; ch < 4; ++ch) {
        if (ch < 3) {
            const float* s = Tw + (size_t)(i_base + 5 * (ch + 1)) * 672;
            float* d = tc[(ch + 1) & 1];
            GLL(s + 4 * t, d + 4 * t);
            GLL(s + 4 * (512 + t), d + 4 * (512 + t));
            asm volatile("s_waitcnt vmcnt(2)" ::: "memory");  // chunk ch landed
        } else {
            asm volatile("s_waitcnt vmcnt(0)" ::: "memory");
        }
        __builtin_amdgcn_s_barrier();
        asm volatile("" ::: "memory");

        const int ni = (ch == 3 && iq == 3) ? 6 : 5;
        const float* tcb = tc[ch & 1];
        #pragma unroll 1
        for (int ii = 0; ii < ni; ++ii) {
            float h0k[4], h1k[4];
            #pragma unroll
            for (int k = 0; k < 4; ++k) {
                h0k[k] = h_s[q0 * 256 + lane + 64 * k];
                h1k[k] = h_s[(9 + q1) * 256 + lane + 64 * k];
            }
            const float* tb = tcb + ii * 672 + widr * 84;   // r = widr
            float dd[4] = {0.f, 0.f, 0.f, 0.f};
            #pragma unroll
            for (int jt = 0; jt < 3; ++jt) {
                const float4* tp = (const float4*)(tb + jt * 28);
                float s[28];
                #pragma unroll
                for (int m = 0; m < 7; ++m) *(float4*)(s + 4 * m) = tp[m];
                #pragma unroll
                for (int k = 0; k < 4; ++k) {
                    float e0 = 0.f, e1 = 0.f, e2 = 0.f;
                    #pragma unroll
                    for (int m = 0; m < 9; ++m) {
                        e0 = fmaf(s[m],      h3v[k][m], e0);
                        e1 = fmaf(s[9 + m],  h3v[k][m], e1);
                        e2 = fmaf(s[18 + m], h3v[k][m], e2);
                    }
                    dd[k] = fmaf(h2v[k][3 * jt], e0, fmaf(h2v[k][3 * jt + 1], e1,
                            fmaf(h2v[k][3 * jt + 2], e2, dd[k])));
                }
            }
            #pragma unroll
            for (int k = 0; k < 4; ++k) A[k] = fmaf(h0k[k] * h1k[k], dd[k], A[k]);
            if (++q1 == 9) { q1 = 0; ++q0; }
        }
        asm volatile("" ::: "memory");
        __builtin_amdgcn_s_barrier();   // buffer reuse safe
    }

    size_t rb = (size_t)iq * RIS_Q + ((size_t)a * 8192 + b0) * 8 + widr;
    #pragma unroll
    for (int k = 0; k < 4; ++k)
        risP[rb + (size_t)(lane + 64 * k) * 8] = A[k];
}

// ---------------- K3: reduce 4 iq-partials + output projection ----------------
__global__ __launch_bounds__(256, 8) void k3_out(
    const float* __restrict__ risP, const float* __restrict__ Uo,
    const float* __restrict__ bo, float* __restrict__ out) {
    __shared__ float uo_s[8192];
    __shared__ float bo_s[1024];
    __shared__ float ris_s[16 * 32];
    const int t  = threadIdx.x;
    const int b0 = blockIdx.x << 4;
    for (int idx = t; idx < 8192; idx += 256) uo_s[idx] = Uo[idx];
    for (int idx = t; idx < 1024; idx += 256) bo_s[idx] = bo[idx];
    for (int idx = t; idx < 512; idx += 256) {
        int bb = idx >> 5, rem = idx & 31, aa = rem >> 3, rr = rem & 7;
        size_t ro = ((size_t)aa * 8192 + b0 + bb) * 8 + rr;
        ris_s[bb * 32 + rem] = risP[ro] + risP[RIS_Q + ro]
                             + risP[2 * RIS_Q + ro] + risP[3 * RIS_Q + ro];
    }
    __syncthreads();
    const int a  = t >> 6;
    const int c4 = (t & 63) << 2;
    float4 u[8];
    #pragma unroll
    for (int r = 0; r < 8; ++r)
        u[r] = *(const float4*)(uo_s + (a << 11) + (r << 8) + c4);
    const float4 b4 = *(const float4*)(bo_s + (a << 8) + c4);
    #pragma unroll 4
    for (int bb = 0; bb < 16; ++bb) {
        const float* rp = ris_s + bb * 32 + a * 8;
        float4 v = b4;
        #pragma unroll
        for (int r = 0; r < 8; ++r) {
            float w = rp[r];
            v.x = fmaf(w, u[r].x, v.x); v.y = fmaf(w, u[r].y, v.y);
            v.z = fmaf(w, u[r].z, v.z); v.w = fmaf(w, u[r].w, v.w);
        }
        *(float4*)(out + (size_t)(b0 + bb) * 1024 + (a << 8) + c4) = v;
    }
}

extern "C" void kernel_launch(void* const* d_in, const int* in_sizes, int n_in,
                              void* d_out, int out_size, void* d_ws, size_t ws_size,
                              hipStream_t stream) {
    (void)in_sizes; (void)n_in; (void)out_size; (void)ws_size;
    const float* nh = (const float*)d_in[0];
    const float* U  = (const float*)d_in[1];
    const float* bi = (const float*)d_in[2];
    const float* Uo = (const float*)d_in[3];
    const float* bo = (const float*)d_in[4];
    const float* T  = (const float*)d_in[5];
    float* outp = (float*)d_out;
    float* ws   = (float*)d_ws;   // needs (217728+1179648+1048576)*4 = 9.79 MB

    t_transpose<<<(TT_ELEMS + 255) / 256, 256, 0, stream>>>(T, ws);
    k1_phasex<<<256, 512, 0, stream>>>(nh, U, bi, ws + WS_HT);
    k2_chain<<<512, 512, 0, stream>>>(ws, ws + WS_HT, ws + WS_RIS);
    k3_out<<<512, 256, 0, stream>>>(ws + WS_RIS, Uo, bo, outp);
}